// Round 5
// baseline (735.591 us; speedup 1.0000x reference)
//
#include <hip/hip_runtime.h>

#define NN 50000
#define EE 800000
#define HEADS 8
#define NEG 0.2f
#define BN_EPS 1e-5f
#define SCAN_B 196   // ceil(NN/256)

typedef unsigned int uint;
typedef unsigned short ushort;

typedef __bf16 bf16x8 __attribute__((ext_vector_type(8)));
typedef float f32x4 __attribute__((ext_vector_type(4)));

__device__ __forceinline__ float bflo(uint u) { return __uint_as_float(u << 16); }
__device__ __forceinline__ float bfhi(uint u) { return __uint_as_float(u & 0xffff0000u); }
__device__ __forceinline__ float bf1(ushort u) { return __uint_as_float(((uint)u) << 16); }
__device__ __forceinline__ ushort f2bf(float f) {
  uint u = __float_as_uint(f);
  u += 0x7fff + ((u >> 16) & 1);   // RTNE
  return (ushort)(u >> 16);
}
__device__ __forceinline__ uint pk2(float a, float b) {
  return (uint)f2bf(a) | ((uint)f2bf(b) << 16);
}
__device__ __forceinline__ float eluf(float v) { return v > 0.f ? v : expm1f(v); }

// ---------------------------------------------------------------- dtype detector (1 wave)
__global__ void k_detect(const uint* __restrict__ xw, const int* __restrict__ ew,
                         int* __restrict__ flags) {
  int l = threadIdx.x;   // 64
  int good = 0, zeros = 0;
#pragma unroll
  for (int j = 0; j < 4; ++j) {
    uint lo = xw[l * 4 + j] & 0xffffu;
    uint ex = (lo >> 7) & 0xffu;
    good += (ex >= 110u && ex <= 140u) ? 1 : 0;
    zeros += (ew[2 * (l * 4 + j) + 1] == 0) ? 1 : 0;
  }
  for (int o = 32; o; o >>= 1) { good += __shfl_down(good, o); zeros += __shfl_down(zeros, o); }
  if (l == 0) { flags[0] = (good >= 128) ? 1 : 0; flags[1] = (zeros >= 200) ? 1 : 0; }
}

// ---------------------------------------------------------------- param gather -> f32 block
// P layout (f32): att_s@0 att_d@256 c_bias@512 g_norm@768 b_norm@1024
//                 b_down@1280 g_down@1344 bb_down@1408 b_up@1472 g_up@1728 bb_up@1984
__global__ void k_params(const void* p0, const void* p1, const void* p2, const void* p3,
                         const void* p4, const void* p5, const void* p6, const void* p7,
                         const void* p8, const void* p9, const void* p10,
                         float* __restrict__ P, const int* __restrict__ flags) {
  const void* srcs[11] = {p0, p1, p2, p3, p4, p5, p6, p7, p8, p9, p10};
  const int sz[11]  = {256, 256, 256, 256, 256, 64, 64, 64, 256, 256, 256};
  const int off[11] = {0, 256, 512, 768, 1024, 1280, 1344, 1408, 1472, 1728, 1984};
  int b = blockIdx.x, t = threadIdx.x;
  if (t < sz[b]) {
    const void* s = srcs[b];
    float v = flags[0] ? bf1(((const ushort*)s)[t]) : ((const float*)s)[t];
    P[off[b] + t] = v;
  }
}

// ---------------------------------------------------------------- LDS-tiled transpose -> bf16
// dst[c][r] = src[r][c] for c<C; rows C..D-1 zero-filled. grid=(R/64, D/64).
__global__ void k_transpose(const void* __restrict__ src, ushort* __restrict__ dst,
                            int R, int C, int D, const int* __restrict__ flags) {
  __shared__ ushort tile[64][65];
  int r0 = blockIdx.x * 64, c0 = blockIdx.y * 64;
  int t = threadIdx.x;
  int tr = t >> 6;        // 0..3
  int tc = t & 63;
  int bf = flags[0];
#pragma unroll
  for (int i = 0; i < 16; ++i) {
    int rl = tr + i * 4;
    int r = r0 + rl, c = c0 + tc;
    float v = 0.f;
    if (r < R && c < C)
      v = bf ? bf1(((const ushort*)src)[(size_t)r * C + c])
             : ((const float*)src)[(size_t)r * C + c];
    tile[rl][tc] = f2bf(v);
  }
  __syncthreads();
#pragma unroll
  for (int i = 0; i < 16; ++i) {
    int cl = tr + i * 4;
    int rl = tc;
    int c = c0 + cl, r = r0 + rl;
    if (c < D && r < R)
      dst[(size_t)c * R + r] = (c < C) ? tile[rl][cl] : (ushort)0;
  }
}

// ---------------------------------------------------------------- edges -> canonical int32 + degree count
__global__ void k_edges(const int* __restrict__ raw, int* __restrict__ sc, int* __restrict__ dc,
                        int* __restrict__ count, const int* __restrict__ flags) {
  int e = blockIdx.x * 256 + threadIdx.x;
  if (e >= EE) return;
  int s, d;
  if (flags[1]) { s = raw[2 * e]; d = raw[2 * (EE + e)]; }   // int64 lo words
  else          { s = raw[e];     d = raw[EE + e]; }
  if ((uint)s >= NN) s = 0;
  if ((uint)d >= NN) d = 0;
  sc[e] = s; dc[e] = d;
  atomicAdd(&count[d], 1);
}

// ---------------------------------------------------------------- GEMM (MFMA bf16)
// C[M,*] = A[M,K] @ Bt[n,K]^T. 128x128 tile, 4 waves, 4x4 MFMA 16x16x32 each.
// grid = (n_blocks, m_blocks): x fastest => A-tile L2 reuse across n-blocks.
// aMode 1: A dtype decided by flags[0] (f32 -> convert in staging). aMode 0: A is bf16.
// mode 0: bf16 stores split: cols<256 -> o_xh, cols>=256 -> o_xres
// mode 1: bf16 store to o_bf [M,NC] (guard gc<NC) + f32 bias add
__global__ __launch_bounds__(256)
void k_gemm(const void* __restrict__ A, const ushort* __restrict__ Bt,
            const int* __restrict__ flags, int aMode,
            int M, int K, int mode,
            ushort* __restrict__ o_xh, ushort* __restrict__ o_xres,
            ushort* __restrict__ o_bf, int NC, const float* __restrict__ bias) {
  __shared__ __align__(16) ushort As[128 * 32];
  __shared__ __align__(16) ushort Bs[128 * 32];
  int t = threadIdx.x;
  int l = t & 63, w = t >> 6;
  int wr = w >> 1, wc = w & 1;
  int lr = l & 15, lq = l >> 4;
  int m0 = blockIdx.y * 128;
  int n0 = blockIdx.x * 128;
  const int af32 = (aMode == 1) && (flags[0] == 0);
  const ushort* Ab = (const ushort*)A;
  const float*  Af = (const float*)A;

  f32x4 acc[4][4];
#pragma unroll
  for (int i = 0; i < 4; ++i)
#pragma unroll
    for (int j = 0; j < 4; ++j) acc[i][j] = (f32x4){0.f, 0.f, 0.f, 0.f};

  for (int kt = 0; kt < K; kt += 32) {
    __syncthreads();
#pragma unroll
    for (int r = 0; r < 2; ++r) {
      int ci = r * 256 + t;
      int m = ci >> 2, ko = (ci & 3) << 3;
      int gm = m0 + m; gm = gm < M ? gm : M - 1;
      if (af32) {
        float4 u0 = *(const float4*)(Af + (size_t)gm * K + kt + ko);
        float4 u1 = *(const float4*)(Af + (size_t)gm * K + kt + ko + 4);
        uint4 o;
        o.x = pk2(u0.x, u0.y); o.y = pk2(u0.z, u0.w);
        o.z = pk2(u1.x, u1.y); o.w = pk2(u1.z, u1.w);
        *(uint4*)(&As[m * 32 + ko]) = o;
      } else {
        *(uint4*)(&As[m * 32 + ko]) = *(const uint4*)(Ab + (size_t)gm * K + kt + ko);
      }
      *(uint4*)(&Bs[m * 32 + ko]) = *(const uint4*)(Bt + (size_t)(n0 + m) * K + kt + ko);
    }
    __syncthreads();
    bf16x8 af[4], bf[4];
#pragma unroll
    for (int i = 0; i < 4; ++i) {
      af[i] = *(const bf16x8*)(&As[(wr * 64 + i * 16 + lr) * 32 + lq * 8]);
      bf[i] = *(const bf16x8*)(&Bs[(wc * 64 + i * 16 + lr) * 32 + lq * 8]);
    }
#pragma unroll
    for (int i = 0; i < 4; ++i)
#pragma unroll
      for (int j = 0; j < 4; ++j)
        acc[i][j] = __builtin_amdgcn_mfma_f32_16x16x32_bf16(af[i], bf[j], acc[i][j], 0, 0, 0);
  }

  // C/D layout: col=lane&15, row=(lane>>4)*4+reg  [m89/m91]
#pragma unroll
  for (int i = 0; i < 4; ++i) {
    int gr0 = m0 + wr * 64 + i * 16 + lq * 4;
#pragma unroll
    for (int j = 0; j < 4; ++j) {
      int gc = n0 + wc * 64 + j * 16 + lr;
#pragma unroll
      for (int r = 0; r < 4; ++r) {
        int row = gr0 + r;
        if (row >= M) continue;
        float v = acc[i][j][r];
        if (mode == 0) {
          if (gc < 256) o_xh[(size_t)row * 256 + gc] = f2bf(v);
          else          o_xres[(size_t)row * 256 + (gc - 256)] = f2bf(v);
        } else {
          if (gc < NC) o_bf[(size_t)row * NC + gc] = f2bf(v + bias[gc]);
        }
      }
    }
  }
}

// ---------------------------------------------------------------- attention dots
__global__ void k_attn(const ushort* __restrict__ xh, const float* __restrict__ P,
                       float* __restrict__ a_src, float* __restrict__ a_dst) {
  int id = blockIdx.x * 256 + threadIdx.x;
  if (id >= NN * HEADS) return;
  int n = id >> 3, h = id & 7;
  const uint4* xr = (const uint4*)(xh + (size_t)n * 256 + h * 32);
  const float4* pa = (const float4*)(P + h * 32);
  const float4* pd = (const float4*)(P + 256 + h * 32);
  float s = 0.f, d = 0.f;
#pragma unroll
  for (int j = 0; j < 4; ++j) {
    uint4 q = xr[j];
    float4 a0 = pa[2 * j], a1 = pa[2 * j + 1];
    float4 d0 = pd[2 * j], d1 = pd[2 * j + 1];
    float x0 = bflo(q.x), x1 = bfhi(q.x), x2 = bflo(q.y), x3 = bfhi(q.y);
    float x4 = bflo(q.z), x5 = bfhi(q.z), x6 = bflo(q.w), x7 = bfhi(q.w);
    s += x0 * a0.x + x1 * a0.y + x2 * a0.z + x3 * a0.w
       + x4 * a1.x + x5 * a1.y + x6 * a1.z + x7 * a1.w;
    d += x0 * d0.x + x1 * d0.y + x2 * d0.z + x3 * d0.w
       + x4 * d1.x + x5 * d1.y + x6 * d1.z + x7 * d1.w;
  }
  a_src[id] = s; a_dst[id] = d;
}

// ---------------------------------------------------------------- hierarchical scan (3 kernels)
__global__ void k_scan_bs(const int* __restrict__ count, int* __restrict__ bsum) {
  __shared__ int s[256];
  int i = blockIdx.x * 256 + threadIdx.x;
  s[threadIdx.x] = (i < NN) ? count[i] : 0;
  __syncthreads();
  for (int off = 128; off > 0; off >>= 1) {
    if (threadIdx.x < off) s[threadIdx.x] += s[threadIdx.x + off];
    __syncthreads();
  }
  if (threadIdx.x == 0) bsum[blockIdx.x] = s[0];
}

__global__ void k_scan_top(const int* __restrict__ bsum, int* __restrict__ boff,
                           int* __restrict__ rowptr) {
  __shared__ int s[256];
  int t = threadIdx.x;
  int v = (t < SCAN_B) ? bsum[t] : 0;
  s[t] = v;
  __syncthreads();
  for (int off = 1; off < 256; off <<= 1) {
    int u = (t >= off) ? s[t - off] : 0;
    __syncthreads();
    s[t] += u;
    __syncthreads();
  }
  boff[t] = s[t] - v;
  if (t == 255) rowptr[NN] = s[255];
}

__global__ void k_scan_wr(const int* __restrict__ count, const int* __restrict__ boff,
                          int* __restrict__ rowptr, int* __restrict__ rowwork) {
  __shared__ int s[256];
  int b = blockIdx.x, t = threadIdx.x;
  int i = b * 256 + t;
  int v = (i < NN) ? count[i] : 0;
  s[t] = v;
  __syncthreads();
  for (int off = 1; off < 256; off <<= 1) {
    int u = (t >= off) ? s[t - off] : 0;
    __syncthreads();
    s[t] += u;
    __syncthreads();
  }
  if (i < NN) {
    int ex = boff[b] + s[t] - v;
    rowptr[i] = ex;
    rowwork[i] = ex;
  }
}

// ---------------------------------------------------------------- scatter edges into CSR order
__global__ void k_scatter(const int* __restrict__ sc, const int* __restrict__ dc,
                          int* __restrict__ rowwork, int* __restrict__ perm_src) {
  int e = blockIdx.x * 256 + threadIdx.x;
  if (e >= EE) return;
  int pos = atomicAdd(&rowwork[dc[e]], 1);
  perm_src[pos] = sc[e];
}

// ---------------------------------------------------------------- gather aggregation
// wave per dst node; half-waves take alternating edges; 16B/lane xh loads; 1-deep prefetch.
__global__ __launch_bounds__(256)
void k_aggregate(const int* __restrict__ rowptr, const int* __restrict__ perm_src,
                 const float* __restrict__ a_src, const float* __restrict__ a_dst,
                 const ushort* __restrict__ xh, const ushort* __restrict__ xres,
                 const float* __restrict__ bias, ushort* __restrict__ outb) {
  int n = blockIdx.x * 4 + (threadIdx.x >> 6);
  int l = threadIdx.x & 63;
  if (n >= NN) return;
  int half = l >> 5;           // 0: even edges, 1: odd edges
  int q = l & 31;              // channels 8q..8q+7
  int h = q >> 2;              // head
  float ad = a_dst[n * 8 + h];
  int st = rowptr[n], en = rowptr[n + 1];
  float a0 = 0.f, a1 = 0.f, a2 = 0.f, a3 = 0.f;
  float a4 = 0.f, a5 = 0.f, a6 = 0.f, a7 = 0.f, sum = 0.f;
  int p = st + half;
  int s_c = 0; float e_c = 0.f; uint4 x_c = {0, 0, 0, 0};
  if (p < en) {
    s_c = perm_src[p];
    e_c = a_src[s_c * 8 + h];
    x_c = *(const uint4*)(xh + (size_t)s_c * 256 + q * 8);
  }
  for (; p < en; p += 2) {
    int pn = p + 2;
    int s_n = 0; float e_n = 0.f; uint4 x_n = {0, 0, 0, 0};
    if (pn < en) {
      s_n = perm_src[pn];
      e_n = a_src[s_n * 8 + h];
      x_n = *(const uint4*)(xh + (size_t)s_n * 256 + q * 8);
    }
    float v = e_c + ad;
    v = v > 0.f ? v : NEG * v;
    float wgt = __expf(fminf(v, 60.f));
    sum += wgt;
    a0 += wgt * bflo(x_c.x); a1 += wgt * bfhi(x_c.x);
    a2 += wgt * bflo(x_c.y); a3 += wgt * bfhi(x_c.y);
    a4 += wgt * bflo(x_c.z); a5 += wgt * bfhi(x_c.z);
    a6 += wgt * bflo(x_c.w); a7 += wgt * bfhi(x_c.w);
    s_c = s_n; e_c = e_n; x_c = x_n;
  }
  // combine even/odd halves (lane l <-> l^32)
  sum += __shfl_xor(sum, 32);
  a0 += __shfl_xor(a0, 32); a1 += __shfl_xor(a1, 32);
  a2 += __shfl_xor(a2, 32); a3 += __shfl_xor(a3, 32);
  a4 += __shfl_xor(a4, 32); a5 += __shfl_xor(a5, 32);
  a6 += __shfl_xor(a6, 32); a7 += __shfl_xor(a7, 32);
  if (half == 0) {
    float inv = 1.0f / (sum + 1e-16f);
    int cb = q * 8;
    float4 b0 = *(const float4*)(bias + cb);
    float4 b1 = *(const float4*)(bias + cb + 4);
    uint4 qr = *(const uint4*)(xres + (size_t)n * 256 + cb);
    uint4 pk;
    pk.x = pk2(a0 * inv + b0.x + bflo(qr.x), a1 * inv + b0.y + bfhi(qr.x));
    pk.y = pk2(a2 * inv + b0.z + bflo(qr.y), a3 * inv + b0.w + bfhi(qr.y));
    pk.z = pk2(a4 * inv + b1.x + bflo(qr.z), a5 * inv + b1.y + bfhi(qr.z));
    pk.w = pk2(a6 * inv + b1.z + bflo(qr.w), a7 * inv + b1.w + bfhi(qr.w));
    *(uint4*)(outb + (size_t)n * 256 + cb) = pk;
  }
}

// ---------------------------------------------------------------- BN batch stats on bf16 (sum, sumsq)
// thread owns a channel PAIR; C power of two.
__global__ void k_stats_bf(const ushort* __restrict__ x, float* __restrict__ sums, int n, int C) {
  int t = threadIdx.x;
  int half = C >> 1;
  int c2 = t & (half - 1);
  int rl = t / half;
  int rpb = 256 / half;
  int rows = (n + gridDim.x - 1) / gridDim.x;
  int r0 = blockIdx.x * rows;
  int r1 = r0 + rows; if (r1 > n) r1 = n;
  const uint* xu = (const uint*)x;
  float s0 = 0.f, ss0 = 0.f, s1 = 0.f, ss1 = 0.f;
  for (int r = r0 + rl; r < r1; r += rpb) {
    uint qv = xu[(size_t)r * half + c2];
    float v0 = bflo(qv), v1 = bfhi(qv);
    s0 += v0; ss0 += v0 * v0;
    s1 += v1; ss1 += v1 * v1;
  }
  atomicAdd(&sums[2 * c2], s0);
  atomicAdd(&sums[2 * c2 + 1], s1);
  atomicAdd(&sums[C + 2 * c2], ss0);
  atomicAdd(&sums[C + 2 * c2 + 1], ss1);
}

// ---------------------------------------------------------------- h1b = bf16(elu(bn(out_gat_b)))
__global__ void k_bnact1(const ushort* __restrict__ xin, const float* __restrict__ sums,
                         const float* __restrict__ g, const float* __restrict__ b,
                         ushort* __restrict__ h1b) {
  int id = blockIdx.x * 256 + threadIdx.x;
  size_t base = (size_t)id * 4;
  if (base >= (size_t)NN * 256) return;
  int c = (int)(base & 255);
  const float invN = 1.0f / NN;
  float4 sm = *(const float4*)(sums + c);
  float4 sq = *(const float4*)(sums + 256 + c);
  float4 g4 = *(const float4*)(g + c);
  float4 b4 = *(const float4*)(b + c);
  uint2 qv = *(const uint2*)(xin + base);
  float vv[4] = {bflo(qv.x), bfhi(qv.x), bflo(qv.y), bfhi(qv.y)};
  float smv[4] = {sm.x, sm.y, sm.z, sm.w}, sqv[4] = {sq.x, sq.y, sq.z, sq.w};
  float gv[4] = {g4.x, g4.y, g4.z, g4.w}, bv[4] = {b4.x, b4.y, b4.z, b4.w};
  float o[4];
#pragma unroll
  for (int j = 0; j < 4; ++j) {
    float mean = smv[j] * invN;
    float var = sqv[j] * invN - mean * mean;
    float sc = gv[j] * rsqrtf(var + BN_EPS);
    o[j] = eluf((vv[j] - mean) * sc + bv[j]);
  }
  uint2 pk;
  pk.x = pk2(o[0], o[1]);
  pk.y = pk2(o[2], o[3]);
  *(uint2*)(h1b + base) = pk;
}

// ---------------------------------------------------------------- d_b = bf16(elu(bn(d_pre_b)))
__global__ void k_bnact2(const ushort* __restrict__ xin, const float* __restrict__ sums,
                         const float* __restrict__ g, const float* __restrict__ b,
                         ushort* __restrict__ db) {
  int id = blockIdx.x * 256 + threadIdx.x;
  size_t base = (size_t)id * 4;
  if (base >= (size_t)NN * 64) return;
  int c = (int)(base & 63);
  const float invN = 1.0f / NN;
  float4 sm = *(const float4*)(sums + c);
  float4 sq = *(const float4*)(sums + 64 + c);
  float4 g4 = *(const float4*)(g + c);
  float4 b4 = *(const float4*)(b + c);
  uint2 qv = *(const uint2*)(xin + base);
  float vv[4] = {bflo(qv.x), bfhi(qv.x), bflo(qv.y), bfhi(qv.y)};
  float smv[4] = {sm.x, sm.y, sm.z, sm.w}, sqv[4] = {sq.x, sq.y, sq.z, sq.w};
  float gv[4] = {g4.x, g4.y, g4.z, g4.w}, bv[4] = {b4.x, b4.y, b4.z, b4.w};
  float o[4];
#pragma unroll
  for (int j = 0; j < 4; ++j) {
    float mean = smv[j] * invN;
    float var = sqv[j] * invN - mean * mean;
    float sc = gv[j] * rsqrtf(var + BN_EPS);
    o[j] = eluf((vv[j] - mean) * sc + bv[j]);
  }
  uint2 pk;
  pk.x = pk2(o[0], o[1]);
  pk.y = pk2(o[2], o[3]);
  *(uint2*)(db + base) = pk;
}

// ---------------------------------------------------------------- out = h1 + elu(bn(u_pre_b)) + x
__global__ void k_final(const ushort* __restrict__ upre, const float* __restrict__ sums,
                        const float* __restrict__ g, const float* __restrict__ b,
                        const ushort* __restrict__ h1b, const void* __restrict__ xsrc,
                        void* __restrict__ outv, const int* __restrict__ flags) {
  int id = blockIdx.x * 256 + threadIdx.x;
  size_t base = (size_t)id * 4;
  if (base >= (size_t)NN * 256) return;
  int c = (int)(base & 255);
  const float invN = 1.0f / NN;
  float4 sm = *(const float4*)(sums + c);
  float4 sq = *(const float4*)(sums + 256 + c);
  float4 g4 = *(const float4*)(g + c);
  float4 b4 = *(const float4*)(b + c);
  uint2 qv = *(const uint2*)(upre + base);
  uint2 qh = *(const uint2*)(h1b + base);
  float xv[4];
  if (flags[0]) {
    uint2 qx = *(const uint2*)((const ushort*)xsrc + base);
    xv[0] = bflo(qx.x); xv[1] = bfhi(qx.x); xv[2] = bflo(qx.y); xv[3] = bfhi(qx.y);
  } else {
    float4 qx = *(const float4*)((const float*)xsrc + base);
    xv[0] = qx.x; xv[1] = qx.y; xv[2] = qx.z; xv[3] = qx.w;
  }
  float vv[4] = {bflo(qv.x), bfhi(qv.x), bflo(qv.y), bfhi(qv.y)};
  float hv[4] = {bflo(qh.x), bfhi(qh.x), bflo(qh.y), bfhi(qh.y)};
  float smv[4] = {sm.x, sm.y, sm.z, sm.w}, sqv[4] = {sq.x, sq.y, sq.z, sq.w};
  float gv[4] = {g4.x, g4.y, g4.z, g4.w}, bv[4] = {b4.x, b4.y, b4.z, b4.w};
  float o[4];
#pragma unroll
  for (int j = 0; j < 4; ++j) {
    float mean = smv[j] * invN;
    float var = sqv[j] * invN - mean * mean;
    float sc = gv[j] * rsqrtf(var + BN_EPS);
    o[j] = eluf((vv[j] - mean) * sc + bv[j]) + hv[j] + xv[j];
  }
  if (flags[0]) {
    uint2 pk;
    pk.x = pk2(o[0], o[1]);
    pk.y = pk2(o[2], o[3]);
    *(uint2*)((ushort*)outv + base) = pk;
  } else {
    *(float4*)((float*)outv + base) = make_float4(o[0], o[1], o[2], o[3]);
  }
}

// ================================================================ host
extern "C" void kernel_launch(void* const* d_in, const int* in_sizes, int n_in,
                              void* d_out, int out_size, void* d_ws, size_t ws_size,
                              hipStream_t stream) {
  const void* x      = d_in[0];
  const int*  ei     = (const int*)d_in[1];
  const void* W_lin  = d_in[2];
  const void* att_s  = d_in[3];
  const void* att_d  = d_in[4];
  const void* c_bias = d_in[5];
  const void* W_res  = d_in[6];
  const void* g_norm = d_in[7];
  const void* b_norm = d_in[8];
  const void* W_down = d_in[9];
  const void* b_down = d_in[10];
  const void* g_down = d_in[11];
  const void* bb_down= d_in[12];
  const void* W_up   = d_in[13];
  const void* b_up   = d_in[14];
  const void* g_up   = d_in[15];
  const void* bb_up  = d_in[16];

  char* ws = (char*)d_ws;
  size_t off = 0;
  auto alloc = [&](size_t bytes) -> char* {
    char* p = ws + off;
    off = (off + bytes + 255) & ~(size_t)255;
    return p;
  };
  // ---- zeroed region
  int*   flags  = (int*)alloc(2 * 4);
  int*   count  = (int*)alloc((size_t)NN * 4);
  float* sums1  = (float*)alloc(512 * 4);
  float* sums2  = (float*)alloc(128 * 4);
  float* sums3  = (float*)alloc(512 * 4);
  size_t zbytes = off;
  // ---- rest
  float* P      = (float*)alloc(2240 * 4);
  int* bsum     = (int*)alloc(256 * 4);
  int* boff     = (int*)alloc(256 * 4);
  int* rowptr   = (int*)alloc((size_t)(NN + 1) * 4);
  int* rowwork  = (int*)alloc((size_t)(NN + 1) * 4);
  int* src_c    = (int*)alloc((size_t)EE * 4);
  int* dst_c    = (int*)alloc((size_t)EE * 4);
  int* perm_src = (int*)alloc((size_t)EE * 4);
  ushort* bt1   = (ushort*)alloc((size_t)512 * 256 * 2);
  ushort* bt2   = (ushort*)alloc((size_t)128 * 256 * 2);  // rows 64..127 zero-padded
  ushort* bt3   = (ushort*)alloc((size_t)256 * 64 * 2);
  float* a_src  = (float*)alloc((size_t)NN * 8 * 4);
  float* a_dst  = (float*)alloc((size_t)NN * 8 * 4);
  ushort* xh    = (ushort*)alloc((size_t)NN * 256 * 2);
  ushort* xres  = (ushort*)alloc((size_t)NN * 256 * 2);
  ushort* og_b  = (ushort*)alloc((size_t)NN * 256 * 2);   // out_gat bf16
  ushort* d_b   = (ushort*)alloc((size_t)NN * 64 * 2);
  // ---- aliases (non-overlapping lifetimes)
  ushort* h1b    = xres;   // xres dead after k_aggregate; h1b written in k_bnact1
  ushort* d_pre_b= xh;     // xh dead after k_aggregate; written by GEMM2
  ushort* u_pre_b= og_b;   // og_b dead after k_bnact1/stats1; written by GEMM3

  hipMemsetAsync(d_ws, 0, zbytes, stream);

  hipLaunchKernelGGL(k_detect, dim3(1), dim3(64), 0, stream, (const uint*)x, ei, flags);
  hipLaunchKernelGGL(k_params, dim3(11), dim3(256), 0, stream,
                     att_s, att_d, c_bias, g_norm, b_norm, b_down, g_down, bb_down,
                     b_up, g_up, bb_up, P, flags);
  hipLaunchKernelGGL(k_transpose, dim3(4, 4), dim3(256), 0, stream, W_lin, bt1, 256, 256, 256, flags);
  hipLaunchKernelGGL(k_transpose, dim3(4, 4), dim3(256), 0, stream, W_res, bt1 + 256 * 256, 256, 256, 256, flags);
  hipLaunchKernelGGL(k_transpose, dim3(4, 2), dim3(256), 0, stream, W_down, bt2, 256, 64, 128, flags);
  hipLaunchKernelGGL(k_transpose, dim3(1, 4), dim3(256), 0, stream, W_up, bt3, 64, 256, 256, flags);
  hipLaunchKernelGGL(k_edges, dim3((EE + 255) / 256), dim3(256), 0, stream,
                     ei, src_c, dst_c, count, flags);

  // GEMM1: [xh | xres] = x @ [W_lin | W_res]  (A = raw x, dtype per flag; cast folded into staging)
  hipLaunchKernelGGL(k_gemm, dim3(4, 391), dim3(256), 0, stream, x, bt1, flags, 1,
                     NN, 256, 0, xh, xres, (ushort*)nullptr, 0, (const float*)nullptr);
  hipLaunchKernelGGL(k_attn, dim3((NN * 8 + 255) / 256), dim3(256), 0, stream,
                     xh, P, a_src, a_dst);

  // CSR build: hierarchical scan + scatter
  hipLaunchKernelGGL(k_scan_bs, dim3(SCAN_B), dim3(256), 0, stream, count, bsum);
  hipLaunchKernelGGL(k_scan_top, dim3(1), dim3(256), 0, stream, bsum, boff, rowptr);
  hipLaunchKernelGGL(k_scan_wr, dim3(SCAN_B), dim3(256), 0, stream, count, boff, rowptr, rowwork);
  hipLaunchKernelGGL(k_scatter, dim3((EE + 255) / 256), dim3(256), 0, stream,
                     src_c, dst_c, rowwork, perm_src);

  hipLaunchKernelGGL(k_aggregate, dim3(NN / 4), dim3(256), 0, stream, rowptr, perm_src,
                     a_src, a_dst, xh, xres, P + 512, og_b);

  hipLaunchKernelGGL(k_stats_bf, dim3(256), dim3(256), 0, stream, og_b, sums1, NN, 256);
  hipLaunchKernelGGL(k_bnact1, dim3(NN * 256 / 4 / 256), dim3(256), 0, stream,
                     og_b, sums1, P + 768, P + 1024, h1b);

  // GEMM2: d_pre_b = bf16(h1 @ W_down + b_down)
  hipLaunchKernelGGL(k_gemm, dim3(1, 391), dim3(256), 0, stream, h1b, bt2, flags, 0,
                     NN, 256, 1, (ushort*)nullptr, (ushort*)nullptr, d_pre_b, 64, P + 1280);
  hipLaunchKernelGGL(k_stats_bf, dim3(256), dim3(256), 0, stream, d_pre_b, sums2, NN, 64);
  hipLaunchKernelGGL(k_bnact2, dim3(NN * 64 / 4 / 256), dim3(256), 0, stream,
                     d_pre_b, sums2, P + 1344, P + 1408, d_b);

  // GEMM3: u_pre_b = bf16(d @ W_up + b_up)
  hipLaunchKernelGGL(k_gemm, dim3(2, 391), dim3(256), 0, stream, d_b, bt3, flags, 0,
                     NN, 64, 1, (ushort*)nullptr, (ushort*)nullptr, u_pre_b, 256, P + 1472);
  hipLaunchKernelGGL(k_stats_bf, dim3(256), dim3(256), 0, stream, u_pre_b, sums3, NN, 256);
  hipLaunchKernelGGL(k_final, dim3(NN * 256 / 4 / 256), dim3(256), 0, stream,
                     u_pre_b, sums3, P + 1728, P + 1984, h1b, x, d_out, flags);
}

// Round 6
// 613.613 us; speedup vs baseline: 1.1988x; 1.1988x over previous
//
#include <hip/hip_runtime.h>

#define NN 50000
#define EE 800000
#define HEADS 8
#define NEG 0.2f
#define BN_EPS 1e-5f
#define SCAN_B 196   // ceil(NN/256)
#define STAT_B 64    // stats partial blocks

typedef unsigned int uint;
typedef unsigned short ushort;

typedef __bf16 bf16x8 __attribute__((ext_vector_type(8)));
typedef float f32x4 __attribute__((ext_vector_type(4)));

__device__ __forceinline__ float bflo(uint u) { return __uint_as_float(u << 16); }
__device__ __forceinline__ float bfhi(uint u) { return __uint_as_float(u & 0xffff0000u); }
__device__ __forceinline__ float bf1(ushort u) { return __uint_as_float(((uint)u) << 16); }
__device__ __forceinline__ ushort f2bf(float f) {
  uint u = __float_as_uint(f);
  u += 0x7fff + ((u >> 16) & 1);   // RTNE
  return (ushort)(u >> 16);
}
__device__ __forceinline__ uint pk2(float a, float b) {
  return (uint)f2bf(a) | ((uint)f2bf(b) << 16);
}
__device__ __forceinline__ float eluf(float v) { return v > 0.f ? v : expm1f(v); }

// ---------------------------------------------------------------- dtype detector (1 wave)
__global__ void k_detect(const uint* __restrict__ xw, const int* __restrict__ ew,
                         int* __restrict__ flags) {
  int l = threadIdx.x;   // 64
  int good = 0, zeros = 0;
#pragma unroll
  for (int j = 0; j < 4; ++j) {
    uint lo = xw[l * 4 + j] & 0xffffu;
    uint ex = (lo >> 7) & 0xffu;
    good += (ex >= 110u && ex <= 140u) ? 1 : 0;
    zeros += (ew[2 * (l * 4 + j) + 1] == 0) ? 1 : 0;
  }
  for (int o = 32; o; o >>= 1) { good += __shfl_down(good, o); zeros += __shfl_down(zeros, o); }
  if (l == 0) { flags[0] = (good >= 128) ? 1 : 0; flags[1] = (zeros >= 200) ? 1 : 0; }
}

// ---------------------------------------------------------------- param gather -> f32 block
// P layout (f32): att_s@0 att_d@256 c_bias@512 g_norm@768 b_norm@1024
//                 b_down@1280 g_down@1344 bb_down@1408 b_up@1472 g_up@1728 bb_up@1984
__global__ void k_params(const void* p0, const void* p1, const void* p2, const void* p3,
                         const void* p4, const void* p5, const void* p6, const void* p7,
                         const void* p8, const void* p9, const void* p10,
                         float* __restrict__ P, const int* __restrict__ flags) {
  const void* srcs[11] = {p0, p1, p2, p3, p4, p5, p6, p7, p8, p9, p10};
  const int sz[11]  = {256, 256, 256, 256, 256, 64, 64, 64, 256, 256, 256};
  const int off[11] = {0, 256, 512, 768, 1024, 1280, 1344, 1408, 1472, 1728, 1984};
  int b = blockIdx.x, t = threadIdx.x;
  if (t < sz[b]) {
    const void* s = srcs[b];
    float v = flags[0] ? bf1(((const ushort*)s)[t]) : ((const float*)s)[t];
    P[off[b] + t] = v;
  }
}

// ---------------------------------------------------------------- LDS-tiled transpose -> bf16
__global__ void k_transpose(const void* __restrict__ src, ushort* __restrict__ dst,
                            int R, int C, int D, const int* __restrict__ flags) {
  __shared__ ushort tile[64][65];
  int r0 = blockIdx.x * 64, c0 = blockIdx.y * 64;
  int t = threadIdx.x;
  int tr = t >> 6;        // 0..3
  int tc = t & 63;
  int bf = flags[0];
#pragma unroll
  for (int i = 0; i < 16; ++i) {
    int rl = tr + i * 4;
    int r = r0 + rl, c = c0 + tc;
    float v = 0.f;
    if (r < R && c < C)
      v = bf ? bf1(((const ushort*)src)[(size_t)r * C + c])
             : ((const float*)src)[(size_t)r * C + c];
    tile[rl][tc] = f2bf(v);
  }
  __syncthreads();
#pragma unroll
  for (int i = 0; i < 16; ++i) {
    int cl = tr + i * 4;
    int rl = tc;
    int c = c0 + cl, r = r0 + rl;
    if (c < D && r < R)
      dst[(size_t)c * R + r] = (c < C) ? tile[rl][cl] : (ushort)0;
  }
}

// ---------------------------------------------------------------- edges -> canonical int32 + degree count
__global__ void k_edges(const int* __restrict__ raw, int* __restrict__ sc, int* __restrict__ dc,
                        int* __restrict__ count, const int* __restrict__ flags) {
  int e = blockIdx.x * 256 + threadIdx.x;
  if (e >= EE) return;
  int s, d;
  if (flags[1]) { s = raw[2 * e]; d = raw[2 * (EE + e)]; }   // int64 lo words
  else          { s = raw[e];     d = raw[EE + e]; }
  if ((uint)s >= NN) s = 0;
  if ((uint)d >= NN) d = 0;
  sc[e] = s; dc[e] = d;
  atomicAdd(&count[d], 1);
}

// ---------------------------------------------------------------- GEMM (MFMA bf16)
// C[M,*] = A[M,K] @ Bt[n,K]^T. 128x128 tile, 4 waves, 4x4 MFMA 16x16x32 each.
// grid = (n_blocks, m_blocks): x fastest => A-tile L2 reuse across n-blocks.
// aMode 1: A dtype per flags[0] (f32 -> convert in staging). aMode 0: A is bf16.
// mode 0: bf16 stores split: cols<256 -> o_xh, cols>=256 -> o_xres
// mode 1: bf16 store to o_bf [M,NC] (guard gc<NC) + f32 bias add
__global__ __launch_bounds__(256)
void k_gemm(const void* __restrict__ A, const ushort* __restrict__ Bt,
            const int* __restrict__ flags, int aMode,
            int M, int K, int mode,
            ushort* __restrict__ o_xh, ushort* __restrict__ o_xres,
            ushort* __restrict__ o_bf, int NC, const float* __restrict__ bias) {
  __shared__ __align__(16) ushort As[128 * 32];
  __shared__ __align__(16) ushort Bs[128 * 32];
  int t = threadIdx.x;
  int l = t & 63, w = t >> 6;
  int wr = w >> 1, wc = w & 1;
  int lr = l & 15, lq = l >> 4;
  int m0 = blockIdx.y * 128;
  int n0 = blockIdx.x * 128;
  const int af32 = (aMode == 1) && (flags[0] == 0);
  const ushort* Ab = (const ushort*)A;
  const float*  Af = (const float*)A;

  f32x4 acc[4][4];
#pragma unroll
  for (int i = 0; i < 4; ++i)
#pragma unroll
    for (int j = 0; j < 4; ++j) acc[i][j] = (f32x4){0.f, 0.f, 0.f, 0.f};

  for (int kt = 0; kt < K; kt += 32) {
    __syncthreads();
#pragma unroll
    for (int r = 0; r < 2; ++r) {
      int ci = r * 256 + t;
      int m = ci >> 2, ko = (ci & 3) << 3;
      int gm = m0 + m; gm = gm < M ? gm : M - 1;
      if (af32) {
        float4 u0 = *(const float4*)(Af + (size_t)gm * K + kt + ko);
        float4 u1 = *(const float4*)(Af + (size_t)gm * K + kt + ko + 4);
        uint4 o;
        o.x = pk2(u0.x, u0.y); o.y = pk2(u0.z, u0.w);
        o.z = pk2(u1.x, u1.y); o.w = pk2(u1.z, u1.w);
        *(uint4*)(&As[m * 32 + ko]) = o;
      } else {
        *(uint4*)(&As[m * 32 + ko]) = *(const uint4*)(Ab + (size_t)gm * K + kt + ko);
      }
      *(uint4*)(&Bs[m * 32 + ko]) = *(const uint4*)(Bt + (size_t)(n0 + m) * K + kt + ko);
    }
    __syncthreads();
    bf16x8 af[4], bf[4];
#pragma unroll
    for (int i = 0; i < 4; ++i) {
      af[i] = *(const bf16x8*)(&As[(wr * 64 + i * 16 + lr) * 32 + lq * 8]);
      bf[i] = *(const bf16x8*)(&Bs[(wc * 64 + i * 16 + lr) * 32 + lq * 8]);
    }
#pragma unroll
    for (int i = 0; i < 4; ++i)
#pragma unroll
      for (int j = 0; j < 4; ++j)
        acc[i][j] = __builtin_amdgcn_mfma_f32_16x16x32_bf16(af[i], bf[j], acc[i][j], 0, 0, 0);
  }

  // C/D layout: col=lane&15, row=(lane>>4)*4+reg  [m89/m91]
#pragma unroll
  for (int i = 0; i < 4; ++i) {
    int gr0 = m0 + wr * 64 + i * 16 + lq * 4;
#pragma unroll
    for (int j = 0; j < 4; ++j) {
      int gc = n0 + wc * 64 + j * 16 + lr;
#pragma unroll
      for (int r = 0; r < 4; ++r) {
        int row = gr0 + r;
        if (row >= M) continue;
        float v = acc[i][j][r];
        if (mode == 0) {
          if (gc < 256) o_xh[(size_t)row * 256 + gc] = f2bf(v);
          else          o_xres[(size_t)row * 256 + (gc - 256)] = f2bf(v);
        } else {
          if (gc < NC) o_bf[(size_t)row * NC + gc] = f2bf(v + bias[gc]);
        }
      }
    }
  }
}

// ---------------------------------------------------------------- attention dots
__global__ void k_attn(const ushort* __restrict__ xh, const float* __restrict__ P,
                       float* __restrict__ a_src, float* __restrict__ a_dst) {
  int id = blockIdx.x * 256 + threadIdx.x;
  if (id >= NN * HEADS) return;
  int n = id >> 3, h = id & 7;
  const uint4* xr = (const uint4*)(xh + (size_t)n * 256 + h * 32);
  const float4* pa = (const float4*)(P + h * 32);
  const float4* pd = (const float4*)(P + 256 + h * 32);
  float s = 0.f, d = 0.f;
#pragma unroll
  for (int j = 0; j < 4; ++j) {
    uint4 q = xr[j];
    float4 a0 = pa[2 * j], a1 = pa[2 * j + 1];
    float4 d0 = pd[2 * j], d1 = pd[2 * j + 1];
    float x0 = bflo(q.x), x1 = bfhi(q.x), x2 = bflo(q.y), x3 = bfhi(q.y);
    float x4 = bflo(q.z), x5 = bfhi(q.z), x6 = bflo(q.w), x7 = bfhi(q.w);
    s += x0 * a0.x + x1 * a0.y + x2 * a0.z + x3 * a0.w
       + x4 * a1.x + x5 * a1.y + x6 * a1.z + x7 * a1.w;
    d += x0 * d0.x + x1 * d0.y + x2 * d0.z + x3 * d0.w
       + x4 * d1.x + x5 * d1.y + x6 * d1.z + x7 * d1.w;
  }
  a_src[id] = s; a_dst[id] = d;
}

// ---------------------------------------------------------------- hierarchical scan (3 kernels)
__global__ void k_scan_bs(const int* __restrict__ count, int* __restrict__ bsum) {
  __shared__ int s[256];
  int i = blockIdx.x * 256 + threadIdx.x;
  s[threadIdx.x] = (i < NN) ? count[i] : 0;
  __syncthreads();
  for (int off = 128; off > 0; off >>= 1) {
    if (threadIdx.x < off) s[threadIdx.x] += s[threadIdx.x + off];
    __syncthreads();
  }
  if (threadIdx.x == 0) bsum[blockIdx.x] = s[0];
}

__global__ void k_scan_top(const int* __restrict__ bsum, int* __restrict__ boff,
                           int* __restrict__ rowptr) {
  __shared__ int s[256];
  int t = threadIdx.x;
  int v = (t < SCAN_B) ? bsum[t] : 0;
  s[t] = v;
  __syncthreads();
  for (int off = 1; off < 256; off <<= 1) {
    int u = (t >= off) ? s[t - off] : 0;
    __syncthreads();
    s[t] += u;
    __syncthreads();
  }
  boff[t] = s[t] - v;
  if (t == 255) rowptr[NN] = s[255];
}

__global__ void k_scan_wr(const int* __restrict__ count, const int* __restrict__ boff,
                          int* __restrict__ rowptr, int* __restrict__ rowwork) {
  __shared__ int s[256];
  int b = blockIdx.x, t = threadIdx.x;
  int i = b * 256 + t;
  int v = (i < NN) ? count[i] : 0;
  s[t] = v;
  __syncthreads();
  for (int off = 1; off < 256; off <<= 1) {
    int u = (t >= off) ? s[t - off] : 0;
    __syncthreads();
    s[t] += u;
    __syncthreads();
  }
  if (i < NN) {
    int ex = boff[b] + s[t] - v;
    rowptr[i] = ex;
    rowwork[i] = ex;
  }
}

// ---------------------------------------------------------------- scatter edges into CSR order
__global__ void k_scatter(const int* __restrict__ sc, const int* __restrict__ dc,
                          int* __restrict__ rowwork, int* __restrict__ perm_src) {
  int e = blockIdx.x * 256 + threadIdx.x;
  if (e >= EE) return;
  int pos = atomicAdd(&rowwork[dc[e]], 1);
  perm_src[pos] = sc[e];
}

// ---------------------------------------------------------------- gather aggregation
// wave per dst node; half-waves take alternating edges; 16B/lane xh loads; 1-deep prefetch.
__global__ __launch_bounds__(256)
void k_aggregate(const int* __restrict__ rowptr, const int* __restrict__ perm_src,
                 const float* __restrict__ a_src, const float* __restrict__ a_dst,
                 const ushort* __restrict__ xh, const ushort* __restrict__ xres,
                 const float* __restrict__ bias, ushort* __restrict__ outb) {
  int n = blockIdx.x * 4 + (threadIdx.x >> 6);
  int l = threadIdx.x & 63;
  if (n >= NN) return;
  int half = l >> 5;           // 0: even edges, 1: odd edges
  int q = l & 31;              // channels 8q..8q+7
  int h = q >> 2;              // head
  float ad = a_dst[n * 8 + h];
  int st = rowptr[n], en = rowptr[n + 1];
  float a0 = 0.f, a1 = 0.f, a2 = 0.f, a3 = 0.f;
  float a4 = 0.f, a5 = 0.f, a6 = 0.f, a7 = 0.f, sum = 0.f;
  int p = st + half;
  int s_c = 0; float e_c = 0.f; uint4 x_c = {0, 0, 0, 0};
  if (p < en) {
    s_c = perm_src[p];
    e_c = a_src[s_c * 8 + h];
    x_c = *(const uint4*)(xh + (size_t)s_c * 256 + q * 8);
  }
  for (; p < en; p += 2) {
    int pn = p + 2;
    int s_n = 0; float e_n = 0.f; uint4 x_n = {0, 0, 0, 0};
    if (pn < en) {
      s_n = perm_src[pn];
      e_n = a_src[s_n * 8 + h];
      x_n = *(const uint4*)(xh + (size_t)s_n * 256 + q * 8);
    }
    float v = e_c + ad;
    v = v > 0.f ? v : NEG * v;
    float wgt = __expf(fminf(v, 60.f));
    sum += wgt;
    a0 += wgt * bflo(x_c.x); a1 += wgt * bfhi(x_c.x);
    a2 += wgt * bflo(x_c.y); a3 += wgt * bfhi(x_c.y);
    a4 += wgt * bflo(x_c.z); a5 += wgt * bfhi(x_c.z);
    a6 += wgt * bflo(x_c.w); a7 += wgt * bfhi(x_c.w);
    s_c = s_n; e_c = e_n; x_c = x_n;
  }
  // combine even/odd halves (lane l <-> l^32)
  sum += __shfl_xor(sum, 32);
  a0 += __shfl_xor(a0, 32); a1 += __shfl_xor(a1, 32);
  a2 += __shfl_xor(a2, 32); a3 += __shfl_xor(a3, 32);
  a4 += __shfl_xor(a4, 32); a5 += __shfl_xor(a5, 32);
  a6 += __shfl_xor(a6, 32); a7 += __shfl_xor(a7, 32);
  if (half == 0) {
    float inv = 1.0f / (sum + 1e-16f);
    int cb = q * 8;
    float4 b0 = *(const float4*)(bias + cb);
    float4 b1 = *(const float4*)(bias + cb + 4);
    uint4 qr = *(const uint4*)(xres + (size_t)n * 256 + cb);
    uint4 pk;
    pk.x = pk2(a0 * inv + b0.x + bflo(qr.x), a1 * inv + b0.y + bfhi(qr.x));
    pk.y = pk2(a2 * inv + b0.z + bflo(qr.y), a3 * inv + b0.w + bfhi(qr.y));
    pk.z = pk2(a4 * inv + b1.x + bflo(qr.z), a5 * inv + b1.y + bfhi(qr.z));
    pk.w = pk2(a6 * inv + b1.z + bflo(qr.w), a7 * inv + b1.w + bfhi(qr.w));
    *(uint4*)(outb + (size_t)n * 256 + cb) = pk;
  }
}

// ---------------------------------------------------------------- BN stats stage 1: per-block partials
// ZERO atomics. Each thread owns 4 channels (uint2 load), LDS tree-reduce over row-groups,
// block b writes partial[b*2C .. b*2C+2C): [0,C) = sum, [C,2C) = sumsq.
__global__ __launch_bounds__(256)
void k_stats_p(const ushort* __restrict__ x, float* __restrict__ partial, int n, int C) {
  __shared__ float4 redA[256];
  __shared__ float4 redB[256];
  int t = threadIdx.x, b = blockIdx.x;
  int W = C >> 2;            // uint2 columns per row
  int c4 = t & (W - 1);      // owns channels 4*c4 .. 4*c4+3
  int rl = t / W;
  int G = 256 / W;
  int rows = (n + STAT_B - 1) / STAT_B;
  int r0 = b * rows, r1 = r0 + rows; if (r1 > n) r1 = n;
  const uint2* xu = (const uint2*)x;
  float s0 = 0, s1 = 0, s2 = 0, s3 = 0, q0 = 0, q1 = 0, q2 = 0, q3 = 0;
  for (int r = r0 + rl; r < r1; r += G) {
    uint2 v = xu[(size_t)r * W + c4];
    float v0 = bflo(v.x), v1 = bfhi(v.x), v2 = bflo(v.y), v3 = bfhi(v.y);
    s0 += v0; s1 += v1; s2 += v2; s3 += v3;
    q0 += v0 * v0; q1 += v1 * v1; q2 += v2 * v2; q3 += v3 * v3;
  }
  redA[t] = make_float4(s0, s1, s2, s3);
  redB[t] = make_float4(q0, q1, q2, q3);
  __syncthreads();
  for (int off = 128; off >= W; off >>= 1) {
    if (t < off) {
      float4 a = redA[t + off], c = redA[t];
      redA[t] = make_float4(c.x + a.x, c.y + a.y, c.z + a.z, c.w + a.w);
      float4 d = redB[t + off], e = redB[t];
      redB[t] = make_float4(e.x + d.x, e.y + d.y, e.z + d.z, e.w + d.w);
    }
    __syncthreads();
  }
  if (t < W) {
    float4 a = redA[t], d = redB[t];
    float* ps = partial + (size_t)b * 2 * C;
    ps[4 * c4 + 0] = a.x; ps[4 * c4 + 1] = a.y;
    ps[4 * c4 + 2] = a.z; ps[4 * c4 + 3] = a.w;
    ps[C + 4 * c4 + 0] = d.x; ps[C + 4 * c4 + 1] = d.y;
    ps[C + 4 * c4 + 2] = d.z; ps[C + 4 * c4 + 3] = d.w;
  }
}

// ---------------------------------------------------------------- BN stats stage 2: fold partials
__global__ void k_stats_r(const float* __restrict__ partial, float* __restrict__ sums, int C2) {
  int c = blockIdx.x * 256 + threadIdx.x;
  if (c >= C2) return;
  float s = 0.f;
  for (int b = 0; b < STAT_B; ++b) s += partial[(size_t)b * C2 + c];
  sums[c] = s;
}

// ---------------------------------------------------------------- h1b = bf16(elu(bn(out_gat_b)))
__global__ void k_bnact1(const ushort* __restrict__ xin, const float* __restrict__ sums,
                         const float* __restrict__ g, const float* __restrict__ b,
                         ushort* __restrict__ h1b) {
  int id = blockIdx.x * 256 + threadIdx.x;
  size_t base = (size_t)id * 4;
  if (base >= (size_t)NN * 256) return;
  int c = (int)(base & 255);
  const float invN = 1.0f / NN;
  float4 sm = *(const float4*)(sums + c);
  float4 sq = *(const float4*)(sums + 256 + c);
  float4 g4 = *(const float4*)(g + c);
  float4 b4 = *(const float4*)(b + c);
  uint2 qv = *(const uint2*)(xin + base);
  float vv[4] = {bflo(qv.x), bfhi(qv.x), bflo(qv.y), bfhi(qv.y)};
  float smv[4] = {sm.x, sm.y, sm.z, sm.w}, sqv[4] = {sq.x, sq.y, sq.z, sq.w};
  float gv[4] = {g4.x, g4.y, g4.z, g4.w}, bv[4] = {b4.x, b4.y, b4.z, b4.w};
  float o[4];
#pragma unroll
  for (int j = 0; j < 4; ++j) {
    float mean = smv[j] * invN;
    float var = sqv[j] * invN - mean * mean;
    float sc = gv[j] * rsqrtf(var + BN_EPS);
    o[j] = eluf((vv[j] - mean) * sc + bv[j]);
  }
  uint2 pk;
  pk.x = pk2(o[0], o[1]);
  pk.y = pk2(o[2], o[3]);
  *(uint2*)(h1b + base) = pk;
}

// ---------------------------------------------------------------- d_b = bf16(elu(bn(d_pre_b)))
__global__ void k_bnact2(const ushort* __restrict__ xin, const float* __restrict__ sums,
                         const float* __restrict__ g, const float* __restrict__ b,
                         ushort* __restrict__ db) {
  int id = blockIdx.x * 256 + threadIdx.x;
  size_t base = (size_t)id * 4;
  if (base >= (size_t)NN * 64) return;
  int c = (int)(base & 63);
  const float invN = 1.0f / NN;
  float4 sm = *(const float4*)(sums + c);
  float4 sq = *(const float4*)(sums + 64 + c);
  float4 g4 = *(const float4*)(g + c);
  float4 b4 = *(const float4*)(b + c);
  uint2 qv = *(const uint2*)(xin + base);
  float vv[4] = {bflo(qv.x), bfhi(qv.x), bflo(qv.y), bfhi(qv.y)};
  float smv[4] = {sm.x, sm.y, sm.z, sm.w}, sqv[4] = {sq.x, sq.y, sq.z, sq.w};
  float gv[4] = {g4.x, g4.y, g4.z, g4.w}, bv[4] = {b4.x, b4.y, b4.z, b4.w};
  float o[4];
#pragma unroll
  for (int j = 0; j < 4; ++j) {
    float mean = smv[j] * invN;
    float var = sqv[j] * invN - mean * mean;
    float sc = gv[j] * rsqrtf(var + BN_EPS);
    o[j] = eluf((vv[j] - mean) * sc + bv[j]);
  }
  uint2 pk;
  pk.x = pk2(o[0], o[1]);
  pk.y = pk2(o[2], o[3]);
  *(uint2*)(db + base) = pk;
}

// ---------------------------------------------------------------- out = h1 + elu(bn(u_pre_b)) + x
__global__ void k_final(const ushort* __restrict__ upre, const float* __restrict__ sums,
                        const float* __restrict__ g, const float* __restrict__ b,
                        const ushort* __restrict__ h1b, const void* __restrict__ xsrc,
                        void* __restrict__ outv, const int* __restrict__ flags) {
  int id = blockIdx.x * 256 + threadIdx.x;
  size_t base = (size_t)id * 4;
  if (base >= (size_t)NN * 256) return;
  int c = (int)(base & 255);
  const float invN = 1.0f / NN;
  float4 sm = *(const float4*)(sums + c);
  float4 sq = *(const float4*)(sums + 256 + c);
  float4 g4 = *(const float4*)(g + c);
  float4 b4 = *(const float4*)(b + c);
  uint2 qv = *(const uint2*)(upre + base);
  uint2 qh = *(const uint2*)(h1b + base);
  float xv[4];
  if (flags[0]) {
    uint2 qx = *(const uint2*)((const ushort*)xsrc + base);
    xv[0] = bflo(qx.x); xv[1] = bfhi(qx.x); xv[2] = bflo(qx.y); xv[3] = bfhi(qx.y);
  } else {
    float4 qx = *(const float4*)((const float*)xsrc + base);
    xv[0] = qx.x; xv[1] = qx.y; xv[2] = qx.z; xv[3] = qx.w;
  }
  float vv[4] = {bflo(qv.x), bfhi(qv.x), bflo(qv.y), bfhi(qv.y)};
  float hv[4] = {bflo(qh.x), bfhi(qh.x), bflo(qh.y), bfhi(qh.y)};
  float smv[4] = {sm.x, sm.y, sm.z, sm.w}, sqv[4] = {sq.x, sq.y, sq.z, sq.w};
  float gv[4] = {g4.x, g4.y, g4.z, g4.w}, bv[4] = {b4.x, b4.y, b4.z, b4.w};
  float o[4];
#pragma unroll
  for (int j = 0; j < 4; ++j) {
    float mean = smv[j] * invN;
    float var = sqv[j] * invN - mean * mean;
    float sc = gv[j] * rsqrtf(var + BN_EPS);
    o[j] = eluf((vv[j] - mean) * sc + bv[j]) + hv[j] + xv[j];
  }
  if (flags[0]) {
    uint2 pk;
    pk.x = pk2(o[0], o[1]);
    pk.y = pk2(o[2], o[3]);
    *(uint2*)((ushort*)outv + base) = pk;
  } else {
    *(float4*)((float*)outv + base) = make_float4(o[0], o[1], o[2], o[3]);
  }
}

// ================================================================ host
extern "C" void kernel_launch(void* const* d_in, const int* in_sizes, int n_in,
                              void* d_out, int out_size, void* d_ws, size_t ws_size,
                              hipStream_t stream) {
  const void* x      = d_in[0];
  const int*  ei     = (const int*)d_in[1];
  const void* W_lin  = d_in[2];
  const void* att_s  = d_in[3];
  const void* att_d  = d_in[4];
  const void* c_bias = d_in[5];
  const void* W_res  = d_in[6];
  const void* g_norm = d_in[7];
  const void* b_norm = d_in[8];
  const void* W_down = d_in[9];
  const void* b_down = d_in[10];
  const void* g_down = d_in[11];
  const void* bb_down= d_in[12];
  const void* W_up   = d_in[13];
  const void* b_up   = d_in[14];
  const void* g_up   = d_in[15];
  const void* bb_up  = d_in[16];

  char* ws = (char*)d_ws;
  size_t off = 0;
  auto alloc = [&](size_t bytes) -> char* {
    char* p = ws + off;
    off = (off + bytes + 255) & ~(size_t)255;
    return p;
  };
  // ---- zeroed region (only buffers that accumulate via atomics)
  int*   flags  = (int*)alloc(2 * 4);
  int*   count  = (int*)alloc((size_t)NN * 4);
  size_t zbytes = off;
  // ---- rest
  float* sums1  = (float*)alloc(512 * 4);
  float* sums2  = (float*)alloc(128 * 4);
  float* sums3  = (float*)alloc(512 * 4);
  float* partial= (float*)alloc((size_t)STAT_B * 512 * 4);
  float* P      = (float*)alloc(2240 * 4);
  int* bsum     = (int*)alloc(256 * 4);
  int* boff     = (int*)alloc(256 * 4);
  int* rowptr   = (int*)alloc((size_t)(NN + 1) * 4);
  int* rowwork  = (int*)alloc((size_t)(NN + 1) * 4);
  int* src_c    = (int*)alloc((size_t)EE * 4);
  int* dst_c    = (int*)alloc((size_t)EE * 4);
  int* perm_src = (int*)alloc((size_t)EE * 4);
  ushort* bt1   = (ushort*)alloc((size_t)512 * 256 * 2);
  ushort* bt2   = (ushort*)alloc((size_t)128 * 256 * 2);  // rows 64..127 zero-padded
  ushort* bt3   = (ushort*)alloc((size_t)256 * 64 * 2);
  float* a_src  = (float*)alloc((size_t)NN * 8 * 4);
  float* a_dst  = (float*)alloc((size_t)NN * 8 * 4);
  ushort* xh    = (ushort*)alloc((size_t)NN * 256 * 2);
  ushort* xres  = (ushort*)alloc((size_t)NN * 256 * 2);
  ushort* og_b  = (ushort*)alloc((size_t)NN * 256 * 2);   // out_gat bf16
  ushort* d_b   = (ushort*)alloc((size_t)NN * 64 * 2);
  // ---- aliases (non-overlapping lifetimes)
  ushort* h1b    = xres;   // xres dead after k_aggregate; h1b written in k_bnact1
  ushort* d_pre_b= xh;     // xh dead after k_aggregate; written by GEMM2
  ushort* u_pre_b= og_b;   // og_b dead after k_bnact1/stats1; written by GEMM3

  hipMemsetAsync(d_ws, 0, zbytes, stream);

  hipLaunchKernelGGL(k_detect, dim3(1), dim3(64), 0, stream, (const uint*)x, ei, flags);
  hipLaunchKernelGGL(k_params, dim3(11), dim3(256), 0, stream,
                     att_s, att_d, c_bias, g_norm, b_norm, b_down, g_down, bb_down,
                     b_up, g_up, bb_up, P, flags);
  hipLaunchKernelGGL(k_transpose, dim3(4, 4), dim3(256), 0, stream, W_lin, bt1, 256, 256, 256, flags);
  hipLaunchKernelGGL(k_transpose, dim3(4, 4), dim3(256), 0, stream, W_res, bt1 + 256 * 256, 256, 256, 256, flags);
  hipLaunchKernelGGL(k_transpose, dim3(4, 2), dim3(256), 0, stream, W_down, bt2, 256, 64, 128, flags);
  hipLaunchKernelGGL(k_transpose, dim3(1, 4), dim3(256), 0, stream, W_up, bt3, 64, 256, 256, flags);
  hipLaunchKernelGGL(k_edges, dim3((EE + 255) / 256), dim3(256), 0, stream,
                     ei, src_c, dst_c, count, flags);

  // GEMM1: [xh | xres] = x @ [W_lin | W_res]  (A = raw x; cast folded into staging)
  hipLaunchKernelGGL(k_gemm, dim3(4, 391), dim3(256), 0, stream, x, bt1, flags, 1,
                     NN, 256, 0, xh, xres, (ushort*)nullptr, 0, (const float*)nullptr);
  hipLaunchKernelGGL(k_attn, dim3((NN * 8 + 255) / 256), dim3(256), 0, stream,
                     xh, P, a_src, a_dst);

  // CSR build: hierarchical scan + scatter
  hipLaunchKernelGGL(k_scan_bs, dim3(SCAN_B), dim3(256), 0, stream, count, bsum);
  hipLaunchKernelGGL(k_scan_top, dim3(1), dim3(256), 0, stream, bsum, boff, rowptr);
  hipLaunchKernelGGL(k_scan_wr, dim3(SCAN_B), dim3(256), 0, stream, count, boff, rowptr, rowwork);
  hipLaunchKernelGGL(k_scatter, dim3((EE + 255) / 256), dim3(256), 0, stream,
                     src_c, dst_c, rowwork, perm_src);

  hipLaunchKernelGGL(k_aggregate, dim3(NN / 4), dim3(256), 0, stream, rowptr, perm_src,
                     a_src, a_dst, xh, xres, P + 512, og_b);

  hipLaunchKernelGGL(k_stats_p, dim3(STAT_B), dim3(256), 0, stream, og_b, partial, NN, 256);
  hipLaunchKernelGGL(k_stats_r, dim3(2), dim3(256), 0, stream, partial, sums1, 512);
  hipLaunchKernelGGL(k_bnact1, dim3(NN * 256 / 4 / 256), dim3(256), 0, stream,
                     og_b, sums1, P + 768, P + 1024, h1b);

  // GEMM2: d_pre_b = bf16(h1 @ W_down + b_down)
  hipLaunchKernelGGL(k_gemm, dim3(1, 391), dim3(256), 0, stream, h1b, bt2, flags, 0,
                     NN, 256, 1, (ushort*)nullptr, (ushort*)nullptr, d_pre_b, 64, P + 1280);
  hipLaunchKernelGGL(k_stats_p, dim3(STAT_B), dim3(256), 0, stream, d_pre_b, partial, NN, 64);
  hipLaunchKernelGGL(k_stats_r, dim3(1), dim3(256), 0, stream, partial, sums2, 128);
  hipLaunchKernelGGL(k_bnact2, dim3(NN * 64 / 4 / 256), dim3(256), 0, stream,
                     d_pre_b, sums2, P + 1344, P + 1408, d_b);

  // GEMM3: u_pre_b = bf16(d @ W_up + b_up)
  hipLaunchKernelGGL(k_gemm, dim3(2, 391), dim3(256), 0, stream, d_b, bt3, flags, 0,
                     NN, 64, 1, (ushort*)nullptr, (ushort*)nullptr, u_pre_b, 256, P + 1472);
  hipLaunchKernelGGL(k_stats_p, dim3(STAT_B), dim3(256), 0, stream, u_pre_b, partial, NN, 256);
  hipLaunchKernelGGL(k_stats_r, dim3(2), dim3(256), 0, stream, partial, sums3, 512);
  hipLaunchKernelGGL(k_final, dim3(NN * 256 / 4 / 256), dim3(256), 0, stream,
                     u_pre_b, sums3, P + 1728, P + 1984, h1b, x, d_out, flags);
}